// Round 1
// baseline (1295.378 us; speedup 1.0000x reference)
//
#include <hip/hip_runtime.h>
#include <hip/hip_bf16.h>

// Problem constants (fixed by reference setup_inputs)
constexpr int Bn = 128;   // batch
constexpr int Tn = 32;    // timesteps
constexpr int Dn = 6400;  // input dim
constexpr int Hn = 1000;  // hidden
constexpr int An = 4;     // actions
constexpr int Mn = Bn * Tn;   // 4096 GEMM rows

constexpr int BM = 128, BN = 128, BK = 16;

// ---------------------------------------------------------------------------
// Kernel 1: H1[m, n] = sum_k X[m, k] * W1[n, k] + b1[n]
// X: [M=4096, K=6400] row-major (x[b,t,d], m = b*T+t)
// W1: [N=1000, K=6400] row-major  -> NT layout, both K-contiguous
// fp32 vector-FMA tiled GEMM: 128x128 tile, 256 threads, 8x8 microtile.
// LDS stores tiles transposed [BK][BM+4] so fragment reads are float4.
// ---------------------------------------------------------------------------
__global__ __launch_bounds__(256)
void gemm_xw1(const float* __restrict__ X, const float* __restrict__ W1,
              const float* __restrict__ b1, float* __restrict__ H1)
{
    constexpr int K = Dn;
    constexpr int N = Hn;
    __shared__ float As[BK][BM + 4];   // +4 pad keeps 16B alignment, 2-way write alias only (free)
    __shared__ float Bs[BK][BN + 4];

    const int tid = threadIdx.x;
    const int bm = blockIdx.x * BM;
    const int bn = blockIdx.y * BN;
    const int tx = tid & 15;    // 0..15 -> N direction
    const int ty = tid >> 4;    // 0..15 -> M direction

    float acc[8][8] = {};

    for (int k0 = 0; k0 < K; k0 += BK) {
        // Stage 128x16 A-tile and B-tile: 2 float4 per thread each.
#pragma unroll
        for (int p = 0; p < 2; ++p) {
            const int idx = tid + p * 256;       // 0..511
            const int row = idx >> 2;            // 0..127
            const int k4  = (idx & 3) << 2;      // 0,4,8,12

            const float4 va = *(const float4*)(X + (size_t)(bm + row) * K + k0 + k4);
            As[k4 + 0][row] = va.x;
            As[k4 + 1][row] = va.y;
            As[k4 + 2][row] = va.z;
            As[k4 + 3][row] = va.w;

            const int nrow = bn + row;
            float4 vb = make_float4(0.f, 0.f, 0.f, 0.f);
            if (nrow < N) vb = *(const float4*)(W1 + (size_t)nrow * K + k0 + k4);
            Bs[k4 + 0][row] = vb.x;
            Bs[k4 + 1][row] = vb.y;
            Bs[k4 + 2][row] = vb.z;
            Bs[k4 + 3][row] = vb.w;
        }
        __syncthreads();

#pragma unroll
        for (int kk = 0; kk < BK; ++kk) {
            const float4 a0 = *(const float4*)&As[kk][ty * 8];
            const float4 a1 = *(const float4*)&As[kk][ty * 8 + 4];
            const float4 bb0 = *(const float4*)&Bs[kk][tx * 8];
            const float4 bb1 = *(const float4*)&Bs[kk][tx * 8 + 4];
            const float a[8]  = {a0.x, a0.y, a0.z, a0.w, a1.x, a1.y, a1.z, a1.w};
            const float bv[8] = {bb0.x, bb0.y, bb0.z, bb0.w, bb1.x, bb1.y, bb1.z, bb1.w};
#pragma unroll
            for (int i = 0; i < 8; ++i)
#pragma unroll
                for (int j = 0; j < 8; ++j)
                    acc[i][j] = fmaf(a[i], bv[j], acc[i][j]);
        }
        __syncthreads();
    }

    // Epilogue: add bias, guarded scalar stores (N=1000 not tile-aligned).
#pragma unroll
    for (int i = 0; i < 8; ++i) {
        const int m = bm + ty * 8 + i;
#pragma unroll
        for (int j = 0; j < 8; ++j) {
            const int n = bn + tx * 8 + j;
            if (n < N) H1[(size_t)m * N + n] = acc[i][j] + b1[n];
        }
    }
}

// ---------------------------------------------------------------------------
// Kernel 2: LIF scan. One block per batch element b. Each thread owns 4 hidden
// neurons (h = tid + k*256, H=1000 < 1024). Sequential over T:
//   reset = (mem > 1);  mem = (0.99*mem + cur) * (1-reset);  spk = (mem > 1)
// Layer-2 current h2[a] = sum_h spk1[h] * W2[a,h] via wave shuffle + LDS
// reduction; thread 0 advances mem2 and writes spikes.
// ---------------------------------------------------------------------------
__global__ __launch_bounds__(256)
void snn_scan(const float* __restrict__ H1, const float* __restrict__ W2,
              const float* __restrict__ b2, float* __restrict__ out)
{
    const int b = blockIdx.x;
    const int tid = threadIdx.x;
    const int lane = tid & 63;
    const int wave = tid >> 6;

    float mem1[4] = {0.f, 0.f, 0.f, 0.f};
    float w2[4][An];    // [k][a]
#pragma unroll
    for (int k = 0; k < 4; ++k) {
        const int h = tid + k * 256;
#pragma unroll
        for (int a = 0; a < An; ++a)
            w2[k][a] = (h < Hn) ? W2[a * Hn + h] : 0.f;
    }

    __shared__ float red[4][An];
    float mem2[An] = {0.f, 0.f, 0.f, 0.f};

    for (int t = 0; t < Tn; ++t) {
        float p[An] = {0.f, 0.f, 0.f, 0.f};
#pragma unroll
        for (int k = 0; k < 4; ++k) {
            const int h = tid + k * 256;
            const float cur = (h < Hn) ? H1[((size_t)b * Tn + t) * Hn + h] : 0.f;
            const float reset = (mem1[k] > 1.0f) ? 1.0f : 0.0f;
            const float mnew = (0.99f * mem1[k] + cur) * (1.0f - reset);
            mem1[k] = mnew;
            if (mnew > 1.0f) {
#pragma unroll
                for (int a = 0; a < An; ++a) p[a] += w2[k][a];
            }
        }
        // wave reduction (64 lanes)
#pragma unroll
        for (int off = 32; off > 0; off >>= 1)
#pragma unroll
            for (int a = 0; a < An; ++a) p[a] += __shfl_down(p[a], off, 64);
        if (lane == 0) {
#pragma unroll
            for (int a = 0; a < An; ++a) red[wave][a] = p[a];
        }
        __syncthreads();
        if (tid == 0) {
#pragma unroll
            for (int a = 0; a < An; ++a) {
                const float h2 = red[0][a] + red[1][a] + red[2][a] + red[3][a] + b2[a];
                const float reset2 = (mem2[a] > 1.0f) ? 1.0f : 0.0f;
                const float m2 = (0.99f * mem2[a] + h2) * (1.0f - reset2);
                mem2[a] = m2;
                out[((size_t)b * Tn + t) * An + a] = (m2 > 1.0f) ? 1.0f : 0.0f;
            }
        }
        __syncthreads();   // protect `red` before next iteration writes
    }
}

extern "C" void kernel_launch(void* const* d_in, const int* in_sizes, int n_in,
                              void* d_out, int out_size, void* d_ws, size_t ws_size,
                              hipStream_t stream) {
    const float* x  = (const float*)d_in[0];   // [B,T,D]
    const float* W1 = (const float*)d_in[1];   // [H,D]
    const float* b1 = (const float*)d_in[2];   // [H]
    const float* W2 = (const float*)d_in[3];   // [A,H]
    const float* b2 = (const float*)d_in[4];   // [A]
    float* out = (float*)d_out;                // [B,T,A]
    float* H1  = (float*)d_ws;                 // [M=4096, H=1000] = 16.4 MB scratch

    dim3 grid(Mn / BM, (Hn + BN - 1) / BN);    // 32 x 8
    gemm_xw1<<<grid, 256, 0, stream>>>(x, W1, b1, H1);
    snn_scan<<<Bn, 256, 0, stream>>>(H1, W2, b2, out);
}

// Round 2
// 787.921 us; speedup vs baseline: 1.6440x; 1.6440x over previous
//
#include <hip/hip_runtime.h>
#include <hip/hip_bf16.h>

// Problem constants (fixed by reference setup_inputs)
constexpr int Bn = 128;   // batch
constexpr int Tn = 32;    // timesteps
constexpr int Dn = 6400;  // input dim (K)
constexpr int Hn = 1000;  // hidden  (N)
constexpr int An = 4;     // actions
constexpr int Mn = Bn * Tn;   // 4096 GEMM rows

typedef _Float16 half8 __attribute__((ext_vector_type(8)));
typedef _Float16 half4 __attribute__((ext_vector_type(4)));
typedef float floatx4 __attribute__((ext_vector_type(4)));

// ---------------------------------------------------------------------------
// Kernel 1: H1[m,n] = sum_k X[m,k]*W1[n,k] + b1[n]  via fp16-split MFMA.
//   x = hi + lo/4096  (lo stored pre-scaled by 4096 to stay fp16-normal)
//   acc0 += hi_x*hi_w ; acc1 += hi_x*lo_w + lo_x*hi_w ; H1 = acc0 + acc1/4096
// Error ~3e-7 absolute on h1 (fp32-equivalent for spike thresholding).
// Block 256 thr = 4 waves (2x2), tile 128x128, BK=32, wave tile 64x64,
// 16 output 16x16x32 MFMA tiles/wave, 3 MFMAs each per k-chunk.
// MFMA layouts (m89/m91-verified): A[m=lane&15][k=(lane>>4)*8+j];
// C/D: col=lane&15, row=(lane>>4)*4+reg.
// ---------------------------------------------------------------------------
__global__ __launch_bounds__(256, 2)
void gemm_split16(const float* __restrict__ X, const float* __restrict__ W1,
                  const float* __restrict__ b1, float* __restrict__ H1)
{
    constexpr int K = Dn;
    constexpr int LD = 40;              // f16 row stride: 80 B = 5x16B (aligned b128, 2-way banks max)
    __shared__ _Float16 As[2][128][LD]; // [hi/lo][m][k]
    __shared__ _Float16 Bs[2][128][LD]; // [hi/lo][n][k]

    const int tid = threadIdx.x;
    const int bm = blockIdx.x * 128;
    const int bn = blockIdx.y * 128;
    const int lane = tid & 63;
    const int wid = tid >> 6;
    const int wm = (wid & 1) * 64;
    const int wn = (wid >> 1) * 64;
    const int fr = lane & 15;           // fragment row/col
    const int fq = lane >> 4;           // quad

    floatx4 acc0[4][4] = {};
    floatx4 acc1[4][4] = {};

    for (int k0 = 0; k0 < K; k0 += 32) {
        // ---- stage + convert: 4 float4 per thread per matrix ----
#pragma unroll
        for (int p = 0; p < 4; ++p) {
            const int e = tid + p * 256;        // 0..1023
            const int row = e >> 3;             // 0..127
            const int kq = (e & 7) << 2;        // 0,4,...,28

            // A = X tile
            const float4 va = *(const float4*)(X + (size_t)(bm + row) * K + k0 + kq);
            half4 hi, lo;
            hi[0] = (_Float16)va.x; lo[0] = (_Float16)((va.x - (float)hi[0]) * 4096.0f);
            hi[1] = (_Float16)va.y; lo[1] = (_Float16)((va.y - (float)hi[1]) * 4096.0f);
            hi[2] = (_Float16)va.z; lo[2] = (_Float16)((va.z - (float)hi[2]) * 4096.0f);
            hi[3] = (_Float16)va.w; lo[3] = (_Float16)((va.w - (float)hi[3]) * 4096.0f);
            *(half4*)&As[0][row][kq] = hi;
            *(half4*)&As[1][row][kq] = lo;

            // B = W1 tile (guard rows >= Hn)
            const int nrow = bn + row;
            float4 vb = make_float4(0.f, 0.f, 0.f, 0.f);
            if (nrow < Hn) vb = *(const float4*)(W1 + (size_t)nrow * K + k0 + kq);
            hi[0] = (_Float16)vb.x; lo[0] = (_Float16)((vb.x - (float)hi[0]) * 4096.0f);
            hi[1] = (_Float16)vb.y; lo[1] = (_Float16)((vb.y - (float)hi[1]) * 4096.0f);
            hi[2] = (_Float16)vb.z; lo[2] = (_Float16)((vb.z - (float)hi[2]) * 4096.0f);
            hi[3] = (_Float16)vb.w; lo[3] = (_Float16)((vb.w - (float)hi[3]) * 4096.0f);
            *(half4*)&Bs[0][row][kq] = hi;
            *(half4*)&Bs[1][row][kq] = lo;
        }
        __syncthreads();

        // ---- fragments ----
        half8 ahi[4], alo[4], bhi[4], blo[4];
#pragma unroll
        for (int mt = 0; mt < 4; ++mt) {
            ahi[mt] = *(const half8*)&As[0][wm + mt * 16 + fr][fq * 8];
            alo[mt] = *(const half8*)&As[1][wm + mt * 16 + fr][fq * 8];
        }
#pragma unroll
        for (int nt = 0; nt < 4; ++nt) {
            bhi[nt] = *(const half8*)&Bs[0][wn + nt * 16 + fr][fq * 8];
            blo[nt] = *(const half8*)&Bs[1][wn + nt * 16 + fr][fq * 8];
        }

        // ---- 48 MFMAs ----
#pragma unroll
        for (int mt = 0; mt < 4; ++mt)
#pragma unroll
            for (int nt = 0; nt < 4; ++nt) {
                acc0[mt][nt] = __builtin_amdgcn_mfma_f32_16x16x32_f16(ahi[mt], bhi[nt], acc0[mt][nt], 0, 0, 0);
                acc1[mt][nt] = __builtin_amdgcn_mfma_f32_16x16x32_f16(ahi[mt], blo[nt], acc1[mt][nt], 0, 0, 0);
                acc1[mt][nt] = __builtin_amdgcn_mfma_f32_16x16x32_f16(alo[mt], bhi[nt], acc1[mt][nt], 0, 0, 0);
            }
        __syncthreads();
    }

    // ---- epilogue ----
#pragma unroll
    for (int nt = 0; nt < 4; ++nt) {
        const int n = bn + wn + nt * 16 + fr;
        if (n >= Hn) continue;
        const float bias = b1[n];
#pragma unroll
        for (int mt = 0; mt < 4; ++mt) {
            const int m = bm + wm + mt * 16 + fq * 4;
#pragma unroll
            for (int r = 0; r < 4; ++r)
                H1[(size_t)(m + r) * Hn + n] =
                    acc0[mt][nt][r] + acc1[mt][nt][r] * (1.0f / 4096.0f) + bias;
        }
    }
}

// ---------------------------------------------------------------------------
// Kernel 2: LIF scan (unchanged from round 1 — passed exactly).
// ---------------------------------------------------------------------------
__global__ __launch_bounds__(256)
void snn_scan(const float* __restrict__ H1, const float* __restrict__ W2,
              const float* __restrict__ b2, float* __restrict__ out)
{
    const int b = blockIdx.x;
    const int tid = threadIdx.x;
    const int lane = tid & 63;
    const int wave = tid >> 6;

    float mem1[4] = {0.f, 0.f, 0.f, 0.f};
    float w2[4][An];
#pragma unroll
    for (int k = 0; k < 4; ++k) {
        const int h = tid + k * 256;
#pragma unroll
        for (int a = 0; a < An; ++a)
            w2[k][a] = (h < Hn) ? W2[a * Hn + h] : 0.f;
    }

    __shared__ float red[4][An];
    float mem2[An] = {0.f, 0.f, 0.f, 0.f};

    for (int t = 0; t < Tn; ++t) {
        float p[An] = {0.f, 0.f, 0.f, 0.f};
#pragma unroll
        for (int k = 0; k < 4; ++k) {
            const int h = tid + k * 256;
            const float cur = (h < Hn) ? H1[((size_t)b * Tn + t) * Hn + h] : 0.f;
            const float reset = (mem1[k] > 1.0f) ? 1.0f : 0.0f;
            const float mnew = (0.99f * mem1[k] + cur) * (1.0f - reset);
            mem1[k] = mnew;
            if (mnew > 1.0f) {
#pragma unroll
                for (int a = 0; a < An; ++a) p[a] += w2[k][a];
            }
        }
#pragma unroll
        for (int off = 32; off > 0; off >>= 1)
#pragma unroll
            for (int a = 0; a < An; ++a) p[a] += __shfl_down(p[a], off, 64);
        if (lane == 0) {
#pragma unroll
            for (int a = 0; a < An; ++a) red[wave][a] = p[a];
        }
        __syncthreads();
        if (tid == 0) {
#pragma unroll
            for (int a = 0; a < An; ++a) {
                const float h2 = red[0][a] + red[1][a] + red[2][a] + red[3][a] + b2[a];
                const float reset2 = (mem2[a] > 1.0f) ? 1.0f : 0.0f;
                const float m2 = (0.99f * mem2[a] + h2) * (1.0f - reset2);
                mem2[a] = m2;
                out[((size_t)b * Tn + t) * An + a] = (m2 > 1.0f) ? 1.0f : 0.0f;
            }
        }
        __syncthreads();
    }
}

extern "C" void kernel_launch(void* const* d_in, const int* in_sizes, int n_in,
                              void* d_out, int out_size, void* d_ws, size_t ws_size,
                              hipStream_t stream) {
    const float* x  = (const float*)d_in[0];   // [B,T,D]
    const float* W1 = (const float*)d_in[1];   // [H,D]
    const float* b1 = (const float*)d_in[2];   // [H]
    const float* W2 = (const float*)d_in[3];   // [A,H]
    const float* b2 = (const float*)d_in[4];   // [A]
    float* out = (float*)d_out;                // [B,T,A]
    float* H1  = (float*)d_ws;                 // [M=4096, H=1000] fp32 scratch

    dim3 grid(Mn / 128, (Hn + 127) / 128);     // 32 x 8 = 256 blocks
    gemm_split16<<<grid, 256, 0, stream>>>(x, W1, b1, H1);
    snn_scan<<<Bn, 256, 0, stream>>>(H1, W2, b2, out);
}

// Round 3
// 420.926 us; speedup vs baseline: 3.0775x; 1.8719x over previous
//
#include <hip/hip_runtime.h>
#include <hip/hip_bf16.h>

// Problem constants (fixed by reference setup_inputs)
constexpr int Bn = 128;   // batch
constexpr int Tn = 32;    // timesteps
constexpr int Dn = 6400;  // input dim (K)
constexpr int Hn = 1000;  // hidden  (N)
constexpr int An = 4;     // actions
constexpr int Mn = Bn * Tn;   // 4096 GEMM rows

typedef _Float16 half8 __attribute__((ext_vector_type(8)));
typedef float floatx4 __attribute__((ext_vector_type(4)));

// ---------------------------------------------------------------------------
// GEMM H1[m,n] = sum_k X[m,k]*W1[n,k] + b1[n]  via fp16-split MFMA (absmax 0.0
// verified round 2):  x = hi + lo/4096, acc0 += hi*hi, acc1 += hi*lo + lo*hi.
//
// Round-3 structure: 64x64 tile, BK=64, 256 thr (4 waves, wave-tile 32x32),
// grid 64x16 = 1024 blocks -> 4 blocks/CU (LDS 36 KB, VGPR<=128 via
// launch_bounds(256,4)) for TLP latency hiding; register prefetch of tile k+1
// issued before the MFMAs of tile k for ILP. LDS LD=72 halves: b128 read AND
// write patterns land bank-uniform.
// ---------------------------------------------------------------------------
__global__ __launch_bounds__(256, 4)
void gemm_split16(const float* __restrict__ X, const float* __restrict__ W1,
                  const float* __restrict__ b1, float* __restrict__ H1)
{
    constexpr int K = Dn;
    constexpr int LD = 72;                       // halves; 144 B row stride
    __shared__ __align__(16) _Float16 As[2][64][LD];  // [hi/lo][m][k]
    __shared__ __align__(16) _Float16 Bs[2][64][LD];  // [hi/lo][n][k]

    const int tid = threadIdx.x;
    const int bm = blockIdx.x * 64;
    const int bn = blockIdx.y * 64;
    const int lane = tid & 63;
    const int wid = tid >> 6;
    const int wm = (wid & 1) * 32;
    const int wn = (wid >> 1) * 32;
    const int fr = lane & 15;
    const int fq = lane >> 4;

    // staging map: p in {0,1}: e = tid + p*256 (0..511); row = e>>3 (0..63),
    // k8 = (e&7)*8 : thread owns 8 consecutive k of one row (2 float4 loads).
    const int row0 = tid >> 3;
    const int row1 = (tid + 256) >> 3;
    const int k8_0 = (tid & 7) * 8;
    const int k8_1 = k8_0;                       // (e&7) identical for both p

    float4 rx[2][2], rw[2][2];
    const float zero4[4] = {0.f, 0.f, 0.f, 0.f};

    auto load_tiles = [&](int k0) {
        rx[0][0] = *(const float4*)(X + (size_t)(bm + row0) * K + k0 + k8_0);
        rx[0][1] = *(const float4*)(X + (size_t)(bm + row0) * K + k0 + k8_0 + 4);
        rx[1][0] = *(const float4*)(X + (size_t)(bm + row1) * K + k0 + k8_1);
        rx[1][1] = *(const float4*)(X + (size_t)(bm + row1) * K + k0 + k8_1 + 4);
        const int n0 = bn + row0, n1 = bn + row1;
        if (n0 < Hn) {
            rw[0][0] = *(const float4*)(W1 + (size_t)n0 * K + k0 + k8_0);
            rw[0][1] = *(const float4*)(W1 + (size_t)n0 * K + k0 + k8_0 + 4);
        } else { rw[0][0] = *(const float4*)zero4; rw[0][1] = *(const float4*)zero4; }
        if (n1 < Hn) {
            rw[1][0] = *(const float4*)(W1 + (size_t)n1 * K + k0 + k8_1);
            rw[1][1] = *(const float4*)(W1 + (size_t)n1 * K + k0 + k8_1 + 4);
        } else { rw[1][0] = *(const float4*)zero4; rw[1][1] = *(const float4*)zero4; }
    };

    load_tiles(0);

    floatx4 acc0[2][2] = {};
    floatx4 acc1[2][2] = {};

    for (int k0 = 0; k0 < K; k0 += 64) {
        // ---- convert prefetched regs -> LDS (b128 writes) ----
#pragma unroll
        for (int p = 0; p < 2; ++p) {
            const int row = p ? row1 : row0;
            const int k8 = p ? k8_1 : k8_0;
            float v[8];
            *(float4*)&v[0] = rx[p][0]; *(float4*)&v[4] = rx[p][1];
            half8 hi, lo;
#pragma unroll
            for (int j = 0; j < 8; ++j) {
                hi[j] = (_Float16)v[j];
                lo[j] = (_Float16)((v[j] - (float)hi[j]) * 4096.0f);
            }
            *(half8*)&As[0][row][k8] = hi;
            *(half8*)&As[1][row][k8] = lo;

            *(float4*)&v[0] = rw[p][0]; *(float4*)&v[4] = rw[p][1];
#pragma unroll
            for (int j = 0; j < 8; ++j) {
                hi[j] = (_Float16)v[j];
                lo[j] = (_Float16)((v[j] - (float)hi[j]) * 4096.0f);
            }
            *(half8*)&Bs[0][row][k8] = hi;
            *(half8*)&Bs[1][row][k8] = lo;
        }
        __syncthreads();

        // ---- issue next tile's global loads before compute (ILP) ----
        if (k0 + 64 < K) load_tiles(k0 + 64);

        // ---- compute: 2 k-chunks x 4 tiles x 3 MFMAs ----
#pragma unroll
        for (int c = 0; c < 2; ++c) {
            half8 ahi[2], alo[2], bhi[2], blo[2];
#pragma unroll
            for (int mt = 0; mt < 2; ++mt) {
                ahi[mt] = *(const half8*)&As[0][wm + mt * 16 + fr][c * 32 + fq * 8];
                alo[mt] = *(const half8*)&As[1][wm + mt * 16 + fr][c * 32 + fq * 8];
            }
#pragma unroll
            for (int nt = 0; nt < 2; ++nt) {
                bhi[nt] = *(const half8*)&Bs[0][wn + nt * 16 + fr][c * 32 + fq * 8];
                blo[nt] = *(const half8*)&Bs[1][wn + nt * 16 + fr][c * 32 + fq * 8];
            }
#pragma unroll
            for (int mt = 0; mt < 2; ++mt)
#pragma unroll
                for (int nt = 0; nt < 2; ++nt) {
                    acc0[mt][nt] = __builtin_amdgcn_mfma_f32_16x16x32_f16(ahi[mt], bhi[nt], acc0[mt][nt], 0, 0, 0);
                    acc1[mt][nt] = __builtin_amdgcn_mfma_f32_16x16x32_f16(ahi[mt], blo[nt], acc1[mt][nt], 0, 0, 0);
                    acc1[mt][nt] = __builtin_amdgcn_mfma_f32_16x16x32_f16(alo[mt], bhi[nt], acc1[mt][nt], 0, 0, 0);
                }
        }
        __syncthreads();
    }

    // ---- epilogue: C/D layout col=lane&15, row=fq*4+r ----
#pragma unroll
    for (int nt = 0; nt < 2; ++nt) {
        const int n = bn + wn + nt * 16 + fr;
        if (n >= Hn) continue;
        const float bias = b1[n];
#pragma unroll
        for (int mt = 0; mt < 2; ++mt) {
            const int m = bm + wm + mt * 16 + fq * 4;
#pragma unroll
            for (int r = 0; r < 4; ++r)
                H1[(size_t)(m + r) * Hn + n] =
                    acc0[mt][nt][r] + acc1[mt][nt][r] * (1.0f / 4096.0f) + bias;
        }
    }
}

// ---------------------------------------------------------------------------
// Fused LIF scan: one block per batch element, 1024 threads (h = tid).
// All 32 timestep currents preloaded into registers (32 independent global
// loads, latency-parallel) BEFORE the sequential T-loop, so the barriered
// loop is pure VALU + shuffle. Layer-2 reduce: wave shuffle -> LDS[16][4] ->
// wave-0 shuffle -> lane 0 advances mem2 and writes spikes.
// ---------------------------------------------------------------------------
__global__ __launch_bounds__(1024)
void snn_scan(const float* __restrict__ H1, const float* __restrict__ W2,
              const float* __restrict__ b2, float* __restrict__ out)
{
    const int b = blockIdx.x;
    const int tid = threadIdx.x;
    const int lane = tid & 63;
    const int wid = tid >> 6;
    const bool act = (tid < Hn);

    float cur[Tn];
#pragma unroll
    for (int t = 0; t < Tn; ++t)
        cur[t] = act ? H1[((size_t)b * Tn + t) * Hn + tid] : 0.f;

    float w2[An];
#pragma unroll
    for (int a = 0; a < An; ++a)
        w2[a] = act ? W2[a * Hn + tid] : 0.f;

    __shared__ float red[16][An];
    float mem1 = 0.f;
    float mem2[An] = {0.f, 0.f, 0.f, 0.f};

    for (int t = 0; t < Tn; ++t) {
        const float reset = (mem1 > 1.0f) ? 1.0f : 0.0f;
        mem1 = (0.99f * mem1 + cur[t]) * (1.0f - reset);
        const bool spk = (mem1 > 1.0f);

        float p[An];
#pragma unroll
        for (int a = 0; a < An; ++a) p[a] = spk ? w2[a] : 0.f;

#pragma unroll
        for (int off = 32; off > 0; off >>= 1)
#pragma unroll
            for (int a = 0; a < An; ++a) p[a] += __shfl_down(p[a], off, 64);
        if (lane == 0) {
#pragma unroll
            for (int a = 0; a < An; ++a) red[wid][a] = p[a];
        }
        __syncthreads();

        if (wid == 0) {
            float q[An];
#pragma unroll
            for (int a = 0; a < An; ++a) q[a] = (lane < 16) ? red[lane][a] : 0.f;
#pragma unroll
            for (int off = 8; off > 0; off >>= 1)
#pragma unroll
                for (int a = 0; a < An; ++a) q[a] += __shfl_down(q[a], off, 64);
            if (lane == 0) {
#pragma unroll
                for (int a = 0; a < An; ++a) {
                    const float h2 = q[a] + b2[a];
                    const float reset2 = (mem2[a] > 1.0f) ? 1.0f : 0.0f;
                    const float m2 = (0.99f * mem2[a] + h2) * (1.0f - reset2);
                    mem2[a] = m2;
                    out[((size_t)b * Tn + t) * An + a] = (m2 > 1.0f) ? 1.0f : 0.0f;
                }
            }
        }
        __syncthreads();   // protect red[] before next t's writes
    }
}

extern "C" void kernel_launch(void* const* d_in, const int* in_sizes, int n_in,
                              void* d_out, int out_size, void* d_ws, size_t ws_size,
                              hipStream_t stream) {
    const float* x  = (const float*)d_in[0];   // [B,T,D]
    const float* W1 = (const float*)d_in[1];   // [H,D]
    const float* b1 = (const float*)d_in[2];   // [H]
    const float* W2 = (const float*)d_in[3];   // [A,H]
    const float* b2 = (const float*)d_in[4];   // [A]
    float* out = (float*)d_out;                // [B,T,A]
    float* H1  = (float*)d_ws;                 // [M=4096, H=1000] fp32 scratch

    dim3 grid(Mn / 64, (Hn + 63) / 64);        // 64 x 16 = 1024 blocks
    gemm_split16<<<grid, 256, 0, stream>>>(x, W1, b1, H1);
    snn_scan<<<Bn, 1024, 0, stream>>>(H1, W2, b2, out);
}